// Round 6
// baseline (203.600 us; speedup 1.0000x reference)
//
#include <hip/hip_runtime.h>

#define N_AG    128
#define H_DIM   128
#define IN_DIM  132
#define P_PAIRS 8128          // 128*127/2
#define PPB     4             // pairs per block (one per wave64)
#define BLOCKS  2032          // P_PAIRS / PPB

typedef float f32x4 __attribute__((ext_vector_type(4)));

// closed-form recovery of (i,j) from pair index p (np.triu_indices order)
__device__ __forceinline__ void pair_from_p(int p, int& i, int& j) {
    int t = P_PAIRS - 1 - p;                  // reverse index: t=0 is (N-2,N-1)
    float kf = (sqrtf(8.f * (float)t + 1.f) - 1.f) * 0.5f;
    int k = (int)kf;
    while ((k + 1) * (k + 2) / 2 <= t) ++k;   // fixup fp error
    while (k * (k + 1) / 2 > t) --k;
    i = N_AG - 2 - k;
    j = N_AG - 1 - (t - k * (k + 1) / 2);
}

__global__ void zero_out_kernel(float* out) { out[threadIdx.x] = 0.f; }

// One pair per WAVE64: every weight load is 1 KB contiguous per wave
// (lanes 0..31 -> row 2k, lanes 32..63 -> row 2k+1; elem idx = k*64+lane).
// 4096 streams instead of 8192 -> longer HBM bursts, fewer row conflicts.
// (256,8): VGPR<=64 -> 8 blocks/CU -> all 2032 blocks resident, no turnover.
__global__ __launch_bounds__(256, 8) void fused_mlp_kernel(
    const float* __restrict__ state,
    const float* __restrict__ actions,
    const float* __restrict__ W1,
    const float* __restrict__ b1,
    const float* __restrict__ W2,
    const float* __restrict__ b2,
    const float* __restrict__ W3,
    const float* __restrict__ b3,
    float* __restrict__ out)
{
    const int t    = threadIdx.x;
    const int slot = __builtin_amdgcn_readfirstlane(t >> 6);  // wave id 0..3
    const int lane = t & 63;
    const int h    = lane >> 5;        // row parity within iteration
    const int c    = lane & 31;        // column group (4 cols: 4c..4c+3)
    const int p    = blockIdx.x * PPB + slot;

    __shared__ float xss[PPB][128];    // per-wave private state copy
    __shared__ float h1s[PPB][128];
    __shared__ float h2s[PPB][128];

    xss[slot][lane]      = state[lane];
    xss[slot][lane + 64] = state[lane + 64];

    int i, j;
    pair_from_p(p, i, j);
    const float x128 = (float)i;
    const float x129 = (float)j;
    const float x130 = actions[i];
    const float x131 = actions[j];

    __builtin_amdgcn_wave_barrier();

    // ---- layer 1: h1 = relu(x @ W1[p] + b1[p]) ----
    const f32x4* W1p = (const f32x4*)(W1 + (size_t)p * (IN_DIM * H_DIM));
    f32x4 acc = (f32x4)(0.f);
    #pragma unroll 4
    for (int k = 0; k < 64; ++k) {     // rows 2k (h=0) and 2k+1 (h=1)
        const float xv = xss[slot][2 * k + h];
        const f32x4 w = __builtin_nontemporal_load(&W1p[k * 64 + lane]);
        acc.x = fmaf(xv, w.x, acc.x);
        acc.y = fmaf(xv, w.y, acc.y);
        acc.z = fmaf(xv, w.z, acc.z);
        acc.w = fmaf(xv, w.w, acc.w);
    }
    {   // tail rows 128..131: [i, j, a_i, a_j]
        const f32x4 wA = __builtin_nontemporal_load(&W1p[64 * 64 + lane]); // rows 128/129
        const float xa = h ? x129 : x128;
        acc.x = fmaf(xa, wA.x, acc.x); acc.y = fmaf(xa, wA.y, acc.y);
        acc.z = fmaf(xa, wA.z, acc.z); acc.w = fmaf(xa, wA.w, acc.w);
        const f32x4 wB = __builtin_nontemporal_load(&W1p[65 * 64 + lane]); // rows 130/131
        const float xb = h ? x131 : x130;
        acc.x = fmaf(xb, wB.x, acc.x); acc.y = fmaf(xb, wB.y, acc.y);
        acc.z = fmaf(xb, wB.z, acc.z); acc.w = fmaf(xb, wB.w, acc.w);
    }
    acc.x += __shfl_xor(acc.x, 32, 64);
    acc.y += __shfl_xor(acc.y, 32, 64);
    acc.z += __shfl_xor(acc.z, 32, 64);
    acc.w += __shfl_xor(acc.w, 32, 64);
    const f32x4 b1v = *(const f32x4*)(b1 + (size_t)p * H_DIM + 4 * c);
    if (h == 0) {
        f32x4 h1v;
        h1v.x = fmaxf(acc.x + b1v.x, 0.f);
        h1v.y = fmaxf(acc.y + b1v.y, 0.f);
        h1v.z = fmaxf(acc.z + b1v.z, 0.f);
        h1v.w = fmaxf(acc.w + b1v.w, 0.f);
        *(f32x4*)&h1s[slot][4 * c] = h1v;
    }
    __builtin_amdgcn_wave_barrier();

    // ---- layer 2: h2 = relu(h1 @ W2[p] + b2[p]) ----
    const f32x4* W2p = (const f32x4*)(W2 + (size_t)p * (H_DIM * H_DIM));
    acc = (f32x4)(0.f);
    #pragma unroll 4
    for (int k = 0; k < 64; ++k) {
        const float hv = h1s[slot][2 * k + h];
        const f32x4 w = __builtin_nontemporal_load(&W2p[k * 64 + lane]);
        acc.x = fmaf(hv, w.x, acc.x);
        acc.y = fmaf(hv, w.y, acc.y);
        acc.z = fmaf(hv, w.z, acc.z);
        acc.w = fmaf(hv, w.w, acc.w);
    }
    acc.x += __shfl_xor(acc.x, 32, 64);
    acc.y += __shfl_xor(acc.y, 32, 64);
    acc.z += __shfl_xor(acc.z, 32, 64);
    acc.w += __shfl_xor(acc.w, 32, 64);
    const f32x4 b2v = *(const f32x4*)(b2 + (size_t)p * H_DIM + 4 * c);
    if (h == 0) {
        f32x4 h2v;
        h2v.x = fmaxf(acc.x + b2v.x, 0.f);
        h2v.y = fmaxf(acc.y + b2v.y, 0.f);
        h2v.z = fmaxf(acc.z + b2v.z, 0.f);
        h2v.w = fmaxf(acc.w + b2v.w, 0.f);
        *(f32x4*)&h2s[slot][4 * c] = h2v;
    }
    __builtin_amdgcn_wave_barrier();

    // ---- layer 3: lane l owns rows 2l,2l+1 of W3 (64 lanes x 16B = whole 1KB) ----
    const f32x4* W3p = (const f32x4*)(W3 + (size_t)p * (H_DIM * 2));
    const f32x4 w3 = __builtin_nontemporal_load(&W3p[lane]);
    const float h2a = h2s[slot][2 * lane];
    const float h2b = h2s[slot][2 * lane + 1];
    float l0 = h2a * w3.x + h2b * w3.z;
    float l1 = h2a * w3.y + h2b * w3.w;
    #pragma unroll
    for (int off = 32; off > 0; off >>= 1) {
        l0 += __shfl_xor(l0, off, 64);
        l1 += __shfl_xor(l1, off, 64);
    }
    if (lane == 0) {
        l0 += b3[2 * p];
        l1 += b3[2 * p + 1];
        const float m  = fmaxf(l0, l1);
        const float e0 = expf(l0 - m), e1 = expf(l1 - m);
        const float inv = 1.f / (e0 + e1);
        const float g0 = e0 * inv, g1 = e1 * inv;
        atomicAdd(&out[2 * i],     g0);
        atomicAdd(&out[2 * i + 1], g1);
        atomicAdd(&out[2 * j],     g0);
        atomicAdd(&out[2 * j + 1], g1);
    }
}

extern "C" void kernel_launch(void* const* d_in, const int* in_sizes, int n_in,
                              void* d_out, int out_size, void* d_ws, size_t ws_size,
                              hipStream_t stream) {
    const float* state   = (const float*)d_in[0];
    const float* actions = (const float*)d_in[1];
    const float* W1      = (const float*)d_in[2];
    const float* b1      = (const float*)d_in[3];
    const float* W2      = (const float*)d_in[4];
    const float* b2      = (const float*)d_in[5];
    const float* W3      = (const float*)d_in[6];
    const float* b3      = (const float*)d_in[7];
    float* out = (float*)d_out;

    zero_out_kernel<<<1, 256, 0, stream>>>(out);
    fused_mlp_kernel<<<BLOCKS, 256, 0, stream>>>(
        state, actions, W1, b1, W2, b2, W3, b3, out);
}

// Round 7
// 172.216 us; speedup vs baseline: 1.1822x; 1.1822x over previous
//
#include <hip/hip_runtime.h>

#define N_AG    128
#define H_DIM   128
#define IN_DIM  132
#define P_PAIRS 8128          // 128*127/2
#define PPB     4             // pairs per block (one per wave64)
#define BLOCKS  2032          // P_PAIRS / PPB

typedef float f32x4 __attribute__((ext_vector_type(4)));

// closed-form recovery of (i,j) from pair index p (np.triu_indices order)
__device__ __forceinline__ void pair_from_p(int p, int& i, int& j) {
    int t = P_PAIRS - 1 - p;                  // reverse index: t=0 is (N-2,N-1)
    float kf = (sqrtf(8.f * (float)t + 1.f) - 1.f) * 0.5f;
    int k = (int)kf;
    while ((k + 1) * (k + 2) / 2 <= t) ++k;   // fixup fp error
    while (k * (k + 1) / 2 > t) --k;
    i = N_AG - 2 - k;
    j = N_AG - 1 - (t - k * (k + 1) / 2);
}

// One pair per WAVE64; 1 KB contiguous weight load per wave per iteration.
// NO atomics: per-pair softmax result goes to gbuf[p] (8 B coalesced store).
__global__ __launch_bounds__(256, 8) void fused_mlp_kernel(
    const float* __restrict__ state,
    const float* __restrict__ actions,
    const float* __restrict__ W1,
    const float* __restrict__ b1,
    const float* __restrict__ W2,
    const float* __restrict__ b2,
    const float* __restrict__ W3,
    const float* __restrict__ b3,
    float2* __restrict__ gbuf)
{
    const int t    = threadIdx.x;
    const int slot = __builtin_amdgcn_readfirstlane(t >> 6);  // wave id 0..3
    const int lane = t & 63;
    const int h    = lane >> 5;        // row parity within iteration
    const int c    = lane & 31;        // column group (4 cols: 4c..4c+3)
    const int p    = blockIdx.x * PPB + slot;

    __shared__ float xss[PPB][128];    // per-wave private state copy
    __shared__ float h1s[PPB][128];
    __shared__ float h2s[PPB][128];

    xss[slot][lane]      = state[lane];
    xss[slot][lane + 64] = state[lane + 64];

    int i, j;
    pair_from_p(p, i, j);
    const float x128 = (float)i;
    const float x129 = (float)j;
    const float x130 = actions[i];
    const float x131 = actions[j];

    __builtin_amdgcn_wave_barrier();

    // ---- layer 1: h1 = relu(x @ W1[p] + b1[p]) ----
    const f32x4* W1p = (const f32x4*)(W1 + (size_t)p * (IN_DIM * H_DIM));
    f32x4 acc = (f32x4)(0.f);
    #pragma unroll 4
    for (int k = 0; k < 64; ++k) {     // rows 2k (h=0) and 2k+1 (h=1)
        const float xv = xss[slot][2 * k + h];
        const f32x4 w = __builtin_nontemporal_load(&W1p[k * 64 + lane]);
        acc.x = fmaf(xv, w.x, acc.x);
        acc.y = fmaf(xv, w.y, acc.y);
        acc.z = fmaf(xv, w.z, acc.z);
        acc.w = fmaf(xv, w.w, acc.w);
    }
    {   // tail rows 128..131: [i, j, a_i, a_j]
        const f32x4 wA = __builtin_nontemporal_load(&W1p[64 * 64 + lane]); // rows 128/129
        const float xa = h ? x129 : x128;
        acc.x = fmaf(xa, wA.x, acc.x); acc.y = fmaf(xa, wA.y, acc.y);
        acc.z = fmaf(xa, wA.z, acc.z); acc.w = fmaf(xa, wA.w, acc.w);
        const f32x4 wB = __builtin_nontemporal_load(&W1p[65 * 64 + lane]); // rows 130/131
        const float xb = h ? x131 : x130;
        acc.x = fmaf(xb, wB.x, acc.x); acc.y = fmaf(xb, wB.y, acc.y);
        acc.z = fmaf(xb, wB.z, acc.z); acc.w = fmaf(xb, wB.w, acc.w);
    }
    acc.x += __shfl_xor(acc.x, 32, 64);
    acc.y += __shfl_xor(acc.y, 32, 64);
    acc.z += __shfl_xor(acc.z, 32, 64);
    acc.w += __shfl_xor(acc.w, 32, 64);
    const f32x4 b1v = *(const f32x4*)(b1 + (size_t)p * H_DIM + 4 * c);
    if (h == 0) {
        f32x4 h1v;
        h1v.x = fmaxf(acc.x + b1v.x, 0.f);
        h1v.y = fmaxf(acc.y + b1v.y, 0.f);
        h1v.z = fmaxf(acc.z + b1v.z, 0.f);
        h1v.w = fmaxf(acc.w + b1v.w, 0.f);
        *(f32x4*)&h1s[slot][4 * c] = h1v;
    }
    __builtin_amdgcn_wave_barrier();

    // ---- layer 2: h2 = relu(h1 @ W2[p] + b2[p]) ----
    const f32x4* W2p = (const f32x4*)(W2 + (size_t)p * (H_DIM * H_DIM));
    acc = (f32x4)(0.f);
    #pragma unroll 4
    for (int k = 0; k < 64; ++k) {
        const float hv = h1s[slot][2 * k + h];
        const f32x4 w = __builtin_nontemporal_load(&W2p[k * 64 + lane]);
        acc.x = fmaf(hv, w.x, acc.x);
        acc.y = fmaf(hv, w.y, acc.y);
        acc.z = fmaf(hv, w.z, acc.z);
        acc.w = fmaf(hv, w.w, acc.w);
    }
    acc.x += __shfl_xor(acc.x, 32, 64);
    acc.y += __shfl_xor(acc.y, 32, 64);
    acc.z += __shfl_xor(acc.z, 32, 64);
    acc.w += __shfl_xor(acc.w, 32, 64);
    const f32x4 b2v = *(const f32x4*)(b2 + (size_t)p * H_DIM + 4 * c);
    if (h == 0) {
        f32x4 h2v;
        h2v.x = fmaxf(acc.x + b2v.x, 0.f);
        h2v.y = fmaxf(acc.y + b2v.y, 0.f);
        h2v.z = fmaxf(acc.z + b2v.z, 0.f);
        h2v.w = fmaxf(acc.w + b2v.w, 0.f);
        *(f32x4*)&h2s[slot][4 * c] = h2v;
    }
    __builtin_amdgcn_wave_barrier();

    // ---- layer 3: lane l owns rows 2l,2l+1 of W3 (64 lanes x 16B = whole 1KB) ----
    const f32x4* W3p = (const f32x4*)(W3 + (size_t)p * (H_DIM * 2));
    const f32x4 w3 = __builtin_nontemporal_load(&W3p[lane]);
    const float h2a = h2s[slot][2 * lane];
    const float h2b = h2s[slot][2 * lane + 1];
    float l0 = h2a * w3.x + h2b * w3.z;
    float l1 = h2a * w3.y + h2b * w3.w;
    #pragma unroll
    for (int off = 32; off > 0; off >>= 1) {
        l0 += __shfl_xor(l0, off, 64);
        l1 += __shfl_xor(l1, off, 64);
    }
    if (lane == 0) {
        l0 += b3[2 * p];
        l1 += b3[2 * p + 1];
        const float m  = fmaxf(l0, l1);
        const float e0 = expf(l0 - m), e1 = expf(l1 - m);
        const float inv = 1.f / (e0 + e1);
        gbuf[p] = make_float2(e0 * inv, e1 * inv);
    }
}

// out[a*2+comp] = sum over the 127 pairs containing agent a.
// gbuf is 65 KB -> L2/L3 resident; pure gather + store, no atomics, no init.
__global__ __launch_bounds__(64) void gather_kernel(
    const float2* __restrict__ gbuf,
    float* __restrict__ out)
{
    const int a    = blockIdx.x >> 1;   // agent
    const int comp = blockIdx.x & 1;    // lambda component
    const int lane = threadIdx.x;       // 0..63

    float s = 0.f;
    #pragma unroll
    for (int r = 0; r < 2; ++r) {
        const int o = lane + 64 * r;    // the other agent
        if (o != a) {
            const int i = min(a, o), j = max(a, o);
            const int p = i * (2 * N_AG - 1 - i) / 2 + (j - i - 1);
            const float2 g = gbuf[p];
            s += comp ? g.y : g.x;
        }
    }
    #pragma unroll
    for (int off = 32; off > 0; off >>= 1)
        s += __shfl_xor(s, off, 64);
    if (lane == 0) out[blockIdx.x] = s;
}

extern "C" void kernel_launch(void* const* d_in, const int* in_sizes, int n_in,
                              void* d_out, int out_size, void* d_ws, size_t ws_size,
                              hipStream_t stream) {
    const float* state   = (const float*)d_in[0];
    const float* actions = (const float*)d_in[1];
    const float* W1      = (const float*)d_in[2];
    const float* b1      = (const float*)d_in[3];
    const float* W2      = (const float*)d_in[4];
    const float* b2      = (const float*)d_in[5];
    const float* W3      = (const float*)d_in[6];
    const float* b3      = (const float*)d_in[7];
    float* out   = (float*)d_out;
    float2* gbuf = (float2*)d_ws;       // P_PAIRS float2 = 65 KB

    fused_mlp_kernel<<<BLOCKS, 256, 0, stream>>>(
        state, actions, W1, b1, W2, b2, W3, b3, gbuf);
    gather_kernel<<<2 * N_AG, 64, 0, stream>>>(gbuf, out);
}